// Round 1
// baseline (2386.158 us; speedup 1.0000x reference)
//
#include <hip/hip_runtime.h>
#include <math.h>

// AttnBlock: GroupNorm(32) -> q,k,v = 1x1 conv -> spatial softmax attention
// -> 1x1 proj -> (x + h)/sqrt(2).  B=4, C=256, H=W=64 (N=4096), fp32.
// Round 1: pure fp32 correctness baseline. Attention is flash-style
// (online softmax), 64q x 64k tiles, 4x4 micro-tiles, b128 LDS reads.

#define BB 4
#define CCH 256
#define NSP 4096
#define NGROUPS 32
#define CPG 8               // channels per group
#define EPSV 1e-5f
#define ATTN_SCALE 0.0625f  // 256^-0.5
#define RSQRT2 0.70710678118654752440f

// ---------------- GroupNorm ----------------
__global__ __launch_bounds__(256) void gn_kernel(
    const float* __restrict__ x, const float* __restrict__ gw,
    const float* __restrict__ gb, float* __restrict__ h) {
  int b = blockIdx.x >> 5;
  int g = blockIdx.x & 31;
  size_t base = ((size_t)b * CCH + (size_t)g * CPG) * NSP;
  const float4* xv = (const float4*)(x + base);
  int tid = threadIdx.x;
  float s = 0.f, ss = 0.f;
  for (int i = tid; i < 8192; i += 256) {  // 8 ch * 4096 = 32768 floats
    float4 v = xv[i];
    s += (v.x + v.y) + (v.z + v.w);
    ss += (v.x * v.x + v.y * v.y) + (v.z * v.z + v.w * v.w);
  }
#pragma unroll
  for (int off = 32; off > 0; off >>= 1) {
    s += __shfl_down(s, off, 64);
    ss += __shfl_down(ss, off, 64);
  }
  __shared__ float rs[4], rss[4], stat[2];
  int wv = tid >> 6;
  if ((tid & 63) == 0) { rs[wv] = s; rss[wv] = ss; }
  __syncthreads();
  if (tid == 0) {
    float S = rs[0] + rs[1] + rs[2] + rs[3];
    float SS = rss[0] + rss[1] + rss[2] + rss[3];
    float mean = S * (1.f / 32768.f);
    float var = SS * (1.f / 32768.f) - mean * mean;
    stat[0] = mean;
    stat[1] = rsqrtf(var + EPSV);
  }
  __syncthreads();
  float mean = stat[0], rstd = stat[1];
  float4* hv = (float4*)(h + base);
  for (int i = tid; i < 8192; i += 256) {
    int c = g * CPG + (i >> 10);  // i/1024 = local channel
    float a = gw[c] * rstd;
    float bb = gb[c] - mean * a;
    float4 v = xv[i];
    float4 o;
    o.x = v.x * a + bb; o.y = v.y * a + bb;
    o.z = v.z * a + bb; o.w = v.w * a + bb;
    hv[i] = o;
  }
}

// ---------------- QKV projections: out[d][n] = sum_c W[c][d] h[c][n] + b[d]
__global__ __launch_bounds__(256) void qkv_kernel(
    const float* __restrict__ h,
    const float* __restrict__ Wq, const float* __restrict__ bq,
    const float* __restrict__ Wk, const float* __restrict__ bk,
    const float* __restrict__ Wv, const float* __restrict__ bv,
    float* __restrict__ qo, float* __restrict__ ko, float* __restrict__ vo) {
  __shared__ __align__(16) float Ws[32][64];
  __shared__ __align__(16) float Hs[32][64];
  int n0 = blockIdx.x * 64;
  int d0 = blockIdx.y * 64;
  int b = blockIdx.z & 3;
  int op = blockIdx.z >> 2;
  const float* W = (op == 0) ? Wq : (op == 1) ? Wk : Wv;
  const float* bias = (op == 0) ? bq : (op == 1) ? bk : bv;
  float* out = (op == 0) ? qo : (op == 1) ? ko : vo;
  const float* hb = h + (size_t)b * CCH * NSP;
  int tid = threadIdx.x;
  int tx = tid & 15, ty = tid >> 4;
  int col = tid & 63, r0 = tid >> 6;
  float acc[4][4] = {};
  for (int c0 = 0; c0 < CCH; c0 += 32) {
#pragma unroll
    for (int r = 0; r < 32; r += 4) {
      Ws[r + r0][col] = W[(size_t)(c0 + r + r0) * CCH + d0 + col];
      Hs[r + r0][col] = hb[(size_t)(c0 + r + r0) * NSP + n0 + col];
    }
    __syncthreads();
    for (int cc = 0; cc < 32; ++cc) {
      float4 w4 = *(const float4*)&Ws[cc][ty * 4];
      float4 h4 = *(const float4*)&Hs[cc][tx * 4];
      const float wr[4] = {w4.x, w4.y, w4.z, w4.w};
      const float hr[4] = {h4.x, h4.y, h4.z, h4.w};
#pragma unroll
      for (int i = 0; i < 4; ++i)
#pragma unroll
        for (int j = 0; j < 4; ++j) acc[i][j] += wr[i] * hr[j];
    }
    __syncthreads();
  }
  float* ob = out + (size_t)b * CCH * NSP;
#pragma unroll
  for (int i = 0; i < 4; ++i) {
    int d = d0 + ty * 4 + i;
    float bi = bias[d];
    float4 r;
    r.x = acc[i][0] + bi; r.y = acc[i][1] + bi;
    r.z = acc[i][2] + bi; r.w = acc[i][3] + bi;
    *(float4*)(ob + (size_t)d * NSP + n0 + tx * 4) = r;
  }
}

// ---------------- flash attention (fp32, online softmax) ----------------
// Per block: 64 queries (n0..n0+63) of batch b; loop over 64-key tiles.
__global__ __launch_bounds__(256) void attn_kernel(
    const float* __restrict__ q, const float* __restrict__ k,
    const float* __restrict__ v, float* __restrict__ o) {
  __shared__ __align__(16) float Qs[32][64];   // [c][n]
  __shared__ __align__(16) float Ks[32][64];   // [c][m]
  __shared__ __align__(16) float Pst[64][68];  // [m][n]  (also epilogue tile)
  __shared__ __align__(16) float Vst[64][68];  // [m][c_local]
  int b = blockIdx.y;
  int n0 = blockIdx.x * 64;
  const float* qb = q + (size_t)b * CCH * NSP;
  const float* kb = k + (size_t)b * CCH * NSP;
  const float* vb = v + (size_t)b * CCH * NSP;
  int tid = threadIdx.x;
  int tx = tid & 15, ty = tid >> 4;
  int col = tid & 63, r0 = tid >> 6;

  float accO[4][16];  // rows n=ty*4+i ; channels c = c4*64 + tx*4 + j
#pragma unroll
  for (int i = 0; i < 4; ++i)
#pragma unroll
    for (int j = 0; j < 16; ++j) accO[i][j] = 0.f;
  float m_run[4] = {-INFINITY, -INFINITY, -INFINITY, -INFINITY};
  float l_run[4] = {0.f, 0.f, 0.f, 0.f};

  for (int m0 = 0; m0 < NSP; m0 += 64) {
    // ---- S = Q^T K over 256 channels, 32-channel LDS chunks ----
    float s[4][4] = {};
    for (int c0 = 0; c0 < CCH; c0 += 32) {
#pragma unroll
      for (int r = 0; r < 32; r += 4) {
        Qs[r + r0][col] = qb[(size_t)(c0 + r + r0) * NSP + n0 + col];
        Ks[r + r0][col] = kb[(size_t)(c0 + r + r0) * NSP + m0 + col];
      }
      __syncthreads();
      for (int cc = 0; cc < 32; ++cc) {
        float4 q4 = *(const float4*)&Qs[cc][ty * 4];
        float4 k4 = *(const float4*)&Ks[cc][tx * 4];
        const float qr[4] = {q4.x, q4.y, q4.z, q4.w};
        const float kr[4] = {k4.x, k4.y, k4.z, k4.w};
#pragma unroll
        for (int i = 0; i < 4; ++i)
#pragma unroll
          for (int j = 0; j < 4; ++j) s[i][j] += qr[i] * kr[j];
      }
      __syncthreads();
    }
    // ---- online softmax; rows reduce across the 16 tx lanes (same wave) ----
    float alpha[4];
#pragma unroll
    for (int i = 0; i < 4; ++i) {
      float mx = -INFINITY;
#pragma unroll
      for (int j = 0; j < 4; ++j) {
        s[i][j] *= ATTN_SCALE;
        mx = fmaxf(mx, s[i][j]);
      }
#pragma unroll
      for (int off = 1; off < 16; off <<= 1) mx = fmaxf(mx, __shfl_xor(mx, off, 16));
      float mnew = fmaxf(m_run[i], mx);
      alpha[i] = __expf(m_run[i] - mnew);
      float ls = 0.f;
#pragma unroll
      for (int j = 0; j < 4; ++j) {
        float p = __expf(s[i][j] - mnew);
        s[i][j] = p;
        ls += p;
      }
#pragma unroll
      for (int off = 1; off < 16; off <<= 1) ls += __shfl_xor(ls, off, 16);
      l_run[i] = l_run[i] * alpha[i] + ls;
      m_run[i] = mnew;
#pragma unroll
      for (int j = 0; j < 4; ++j) Pst[tx * 4 + j][ty * 4 + i] = s[i][j];
#pragma unroll
      for (int j = 0; j < 16; ++j) accO[i][j] *= alpha[i];
    }
    // ---- O += P V^T, 4 chunks of 64 channels ----
#pragma unroll
    for (int c4 = 0; c4 < 4; ++c4) {
#pragma unroll
      for (int r = 0; r < 64; r += 4)
        Vst[col][r + r0] = vb[(size_t)(c4 * 64 + r + r0) * NSP + m0 + col];
      __syncthreads();  // also makes Pst visible
      for (int mm = 0; mm < 64; ++mm) {
        float4 p4 = *(const float4*)&Pst[mm][ty * 4];
        float4 v4 = *(const float4*)&Vst[mm][tx * 4];
        const float pp[4] = {p4.x, p4.y, p4.z, p4.w};
        const float vv[4] = {v4.x, v4.y, v4.z, v4.w};
#pragma unroll
        for (int i = 0; i < 4; ++i)
#pragma unroll
          for (int j = 0; j < 4; ++j) accO[i][c4 * 4 + j] += pp[i] * vv[j];
      }
      __syncthreads();
    }
  }
  // ---- epilogue: normalize, transpose via LDS, coalesced [c][n] store ----
  float linv[4];
#pragma unroll
  for (int i = 0; i < 4; ++i) linv[i] = 1.f / l_run[i];
  float* ob = o + (size_t)b * CCH * NSP;
#pragma unroll
  for (int c4 = 0; c4 < 4; ++c4) {
#pragma unroll
    for (int i = 0; i < 4; ++i)
#pragma unroll
      for (int j = 0; j < 4; ++j)
        Pst[tx * 4 + j][ty * 4 + i] = accO[i][c4 * 4 + j] * linv[i];
    __syncthreads();
#pragma unroll
    for (int r = 0; r < 64; r += 4)
      ob[(size_t)(c4 * 64 + r + r0) * NSP + n0 + col] = Pst[r + r0][col];
    __syncthreads();
  }
}

// ---------------- proj + residual + /sqrt(2) ----------------
__global__ __launch_bounds__(256) void proj_kernel(
    const float* __restrict__ ho, const float* __restrict__ Wp,
    const float* __restrict__ bp, const float* __restrict__ x,
    float* __restrict__ out) {
  __shared__ __align__(16) float Ws[32][64];
  __shared__ __align__(16) float Hs[32][64];
  int n0 = blockIdx.x * 64;
  int d0 = blockIdx.y * 64;
  int b = blockIdx.z;
  const float* hb = ho + (size_t)b * CCH * NSP;
  int tid = threadIdx.x;
  int tx = tid & 15, ty = tid >> 4;
  int col = tid & 63, r0 = tid >> 6;
  float acc[4][4] = {};
  for (int c0 = 0; c0 < CCH; c0 += 32) {
#pragma unroll
    for (int r = 0; r < 32; r += 4) {
      Ws[r + r0][col] = Wp[(size_t)(c0 + r + r0) * CCH + d0 + col];
      Hs[r + r0][col] = hb[(size_t)(c0 + r + r0) * NSP + n0 + col];
    }
    __syncthreads();
    for (int cc = 0; cc < 32; ++cc) {
      float4 w4 = *(const float4*)&Ws[cc][ty * 4];
      float4 h4 = *(const float4*)&Hs[cc][tx * 4];
      const float wr[4] = {w4.x, w4.y, w4.z, w4.w};
      const float hr[4] = {h4.x, h4.y, h4.z, h4.w};
#pragma unroll
      for (int i = 0; i < 4; ++i)
#pragma unroll
        for (int j = 0; j < 4; ++j) acc[i][j] += wr[i] * hr[j];
    }
    __syncthreads();
  }
#pragma unroll
  for (int i = 0; i < 4; ++i) {
    int d = d0 + ty * 4 + i;
    float bi = bp[d];
    size_t off = ((size_t)b * CCH + d) * NSP + n0 + tx * 4;
    float4 xr = *(const float4*)(x + off);
    float4 r;
    r.x = (acc[i][0] + bi + xr.x) * RSQRT2;
    r.y = (acc[i][1] + bi + xr.y) * RSQRT2;
    r.z = (acc[i][2] + bi + xr.z) * RSQRT2;
    r.w = (acc[i][3] + bi + xr.w) * RSQRT2;
    *(float4*)(out + off) = r;
  }
}

extern "C" void kernel_launch(void* const* d_in, const int* in_sizes, int n_in,
                              void* d_out, int out_size, void* d_ws, size_t ws_size,
                              hipStream_t stream) {
  const float* x  = (const float*)d_in[0];
  const float* gw = (const float*)d_in[1];
  const float* gb = (const float*)d_in[2];
  const float* Wq = (const float*)d_in[3];
  const float* bq = (const float*)d_in[4];
  const float* Wk = (const float*)d_in[5];
  const float* bk = (const float*)d_in[6];
  const float* Wv = (const float*)d_in[7];
  const float* bv = (const float*)d_in[8];
  const float* Wp = (const float*)d_in[9];
  const float* bp = (const float*)d_in[10];
  float* out = (float*)d_out;

  const size_t SZ = (size_t)BB * CCH * NSP;  // 4.19M floats per buffer
  float* h  = (float*)d_ws;   // h, later reused as attention output
  float* qb = h + SZ;
  float* kb = qb + SZ;
  float* vb = kb + SZ;        // total 67.1 MB of workspace

  gn_kernel<<<dim3(BB * NGROUPS), dim3(256), 0, stream>>>(x, gw, gb, h);
  qkv_kernel<<<dim3(64, 4, 12), dim3(256), 0, stream>>>(
      h, Wq, bq, Wk, bk, Wv, bv, qb, kb, vb);
  attn_kernel<<<dim3(64, BB), dim3(256), 0, stream>>>(qb, kb, vb, h);
  proj_kernel<<<dim3(64, 4, BB), dim3(256), 0, stream>>>(h, Wp, bp, x, out);
}

// Round 2
// 411.034 us; speedup vs baseline: 5.8053x; 5.8053x over previous
//
#include <hip/hip_runtime.h>
#include <math.h>

// AttnBlock: GroupNorm(32) -> q,k,v 1x1 -> spatial attention -> proj -> resid.
// Round 2: attention core on bf16 MFMA 16x16x32.
//  - qkv kernel emits bf16: q [n][c] (pre-scaled by C^-0.5), k [n][c], v [c][n]
//  - attn: per block 64 queries x all 4096 keys, flash online-softmax.
//    LDS tiles XOR-swizzled (16B chunk ch ^= row&7) -> all frag I/O is b128,
//    ~2-way max bank aliasing (free). K/V register-prefetched 1 tile ahead.

#define BB 4
#define CCH 256
#define NSP 4096
#define EPSV 1e-5f
#define ATTN_SCALE 0.0625f  // 256^-0.5
#define RSQRT2 0.70710678118654752440f

typedef __attribute__((ext_vector_type(8))) short bf16x8;
typedef __attribute__((ext_vector_type(4))) short bf16x4;
typedef __attribute__((ext_vector_type(4))) float f32x4;

__device__ __forceinline__ short f2bf(float f) {
  union { float f; unsigned u; } a; a.f = f;
  unsigned r = a.u + 0x7fffu + ((a.u >> 16) & 1u);  // RTN-even
  return (short)(r >> 16);
}

// ---------------- GroupNorm (unchanged from round 1) ----------------
__global__ __launch_bounds__(256) void gn_kernel(
    const float* __restrict__ x, const float* __restrict__ gw,
    const float* __restrict__ gb, float* __restrict__ h) {
  int b = blockIdx.x >> 5;
  int g = blockIdx.x & 31;
  size_t base = ((size_t)b * CCH + (size_t)g * 8) * NSP;
  const float4* xv = (const float4*)(x + base);
  int tid = threadIdx.x;
  float s = 0.f, ss = 0.f;
  for (int i = tid; i < 8192; i += 256) {
    float4 v = xv[i];
    s += (v.x + v.y) + (v.z + v.w);
    ss += (v.x * v.x + v.y * v.y) + (v.z * v.z + v.w * v.w);
  }
#pragma unroll
  for (int off = 32; off > 0; off >>= 1) {
    s += __shfl_down(s, off, 64);
    ss += __shfl_down(ss, off, 64);
  }
  __shared__ float rs[4], rss[4], stat[2];
  int wv = tid >> 6;
  if ((tid & 63) == 0) { rs[wv] = s; rss[wv] = ss; }
  __syncthreads();
  if (tid == 0) {
    float S = rs[0] + rs[1] + rs[2] + rs[3];
    float SS = rss[0] + rss[1] + rss[2] + rss[3];
    float mean = S * (1.f / 32768.f);
    float var = SS * (1.f / 32768.f) - mean * mean;
    stat[0] = mean;
    stat[1] = rsqrtf(var + EPSV);
  }
  __syncthreads();
  float mean = stat[0], rstd = stat[1];
  float4* hv = (float4*)(h + base);
  for (int i = tid; i < 8192; i += 256) {
    int c = g * 8 + (i >> 10);
    float a = gw[c] * rstd;
    float bb = gb[c] - mean * a;
    float4 v = xv[i];
    float4 o;
    o.x = v.x * a + bb; o.y = v.y * a + bb;
    o.z = v.z * a + bb; o.w = v.w * a + bb;
    hv[i] = o;
  }
}

// ---------------- QKV: fp32 GEMM, bf16 outputs in MFMA-friendly layouts ----
__global__ __launch_bounds__(256) void qkv_kernel(
    const float* __restrict__ h,
    const float* __restrict__ Wq, const float* __restrict__ bq,
    const float* __restrict__ Wk, const float* __restrict__ bk,
    const float* __restrict__ Wv, const float* __restrict__ bv,
    short* __restrict__ qo, short* __restrict__ ko, short* __restrict__ vo) {
  __shared__ __align__(16) float Ws[32][64];
  __shared__ __align__(16) float Hs[32][64];
  __shared__ __align__(16) float Ts[64][68];
  int n0 = blockIdx.x * 64;
  int d0 = blockIdx.y * 64;
  int b = blockIdx.z & 3;
  int op = blockIdx.z >> 2;
  const float* W = (op == 0) ? Wq : (op == 1) ? Wk : Wv;
  const float* bias = (op == 0) ? bq : (op == 1) ? bk : bv;
  const float* hb = h + (size_t)b * CCH * NSP;
  int tid = threadIdx.x;
  int tx = tid & 15, ty = tid >> 4;
  int col = tid & 63, r0 = tid >> 6;
  float acc[4][4] = {};
  for (int c0 = 0; c0 < CCH; c0 += 32) {
#pragma unroll
    for (int r = 0; r < 32; r += 4) {
      Ws[r + r0][col] = W[(size_t)(c0 + r + r0) * CCH + d0 + col];
      Hs[r + r0][col] = hb[(size_t)(c0 + r + r0) * NSP + n0 + col];
    }
    __syncthreads();
    for (int cc = 0; cc < 32; ++cc) {
      float4 w4 = *(const float4*)&Ws[cc][ty * 4];
      float4 h4 = *(const float4*)&Hs[cc][tx * 4];
      const float wr[4] = {w4.x, w4.y, w4.z, w4.w};
      const float hr[4] = {h4.x, h4.y, h4.z, h4.w};
#pragma unroll
      for (int i = 0; i < 4; ++i)
#pragma unroll
        for (int j = 0; j < 4; ++j) acc[i][j] += wr[i] * hr[j];
    }
    __syncthreads();
  }
  if (op == 2) {  // v: [c][n] bf16, direct coalesced store
    short* ob = vo + (size_t)b * CCH * NSP;
#pragma unroll
    for (int i = 0; i < 4; ++i) {
      int d = d0 + ty * 4 + i;
      float bi = bias[d];
      bf16x4 r;
      r[0] = f2bf(acc[i][0] + bi); r[1] = f2bf(acc[i][1] + bi);
      r[2] = f2bf(acc[i][2] + bi); r[3] = f2bf(acc[i][3] + bi);
      *(bf16x4*)(ob + (size_t)d * NSP + n0 + tx * 4) = r;
    }
  } else {  // q/k: transpose to [n][c] bf16 (q pre-scaled)
    float sc = (op == 0) ? ATTN_SCALE : 1.f;
#pragma unroll
    for (int i = 0; i < 4; ++i) {
      int d = d0 + ty * 4 + i;
      float bi = bias[d];
#pragma unroll
      for (int j = 0; j < 4; ++j) Ts[tx * 4 + j][ty * 4 + i] = (acc[i][j] + bi) * sc;
    }
    __syncthreads();
    short* ob = ((op == 0) ? qo : ko) + (size_t)b * NSP * CCH;
    int row = tid >> 2, cg = tid & 3;
    short* dst = ob + (size_t)(n0 + row) * CCH + d0 + cg * 16;
#pragma unroll
    for (int j = 0; j < 4; ++j) {
      float4 f = *(float4*)&Ts[row][cg * 16 + j * 4];
      bf16x4 r;
      r[0] = f2bf(f.x); r[1] = f2bf(f.y); r[2] = f2bf(f.z); r[3] = f2bf(f.w);
      *(bf16x4*)(dst + j * 4) = r;
    }
  }
}

// ---------------- flash attention, bf16 MFMA 16x16x32 ----------------
// q,k: [b][n][c] bf16 (q pre-scaled); v: [b][c][n] bf16; out: [b][c][n] fp32.
// Block: 64 queries x 4096 keys. Wave w owns query rows w*16..w*16+15.
__global__ __launch_bounds__(256) void attn_kernel(
    const short* __restrict__ q, const short* __restrict__ k,
    const short* __restrict__ v, float* __restrict__ o) {
  __shared__ __align__(16) unsigned char smem[73728];
  short* Ks = (short*)smem;            // [64 m][256 c], 512B rows, swizzled
  short* Vs = (short*)(smem + 32768);  // [256 c][64 m], 128B rows, swizzled
  short* Ps = (short*)(smem + 65536);  // [4 w][16 n][64 m], 128B rows, swizzled
  float* Fo = (float*)smem;            // epilogue [256 c][68], aliases Ks+Vs

  int b = blockIdx.x & 3;                 // XCD x serves batch x&3 (L2 locality)
  int n0 = (blockIdx.x >> 2) << 6;
  const short* qb = q + (size_t)b * NSP * CCH;
  const short* kb = k + (size_t)b * NSP * CCH;
  const short* vb = v + (size_t)b * CCH * NSP;
  int tid = threadIdx.x;
  int w = tid >> 6, lane = tid & 63, quad = lane >> 4, l16 = lane & 15;

  // staging geometry (loop-invariant): K rows krow0+8i, V rows vrow0+32i
  int krow0 = tid >> 5, kch = tid & 31;
  int vrow0 = tid >> 3, vch = tid & 7;
  int koff = (kch ^ (krow0 & 7)) * 8;  // swizzled chunk offset (const: +8i keeps row&7)
  int voff = (vch ^ (vrow0 & 7)) * 8;

  // ---- stage Q (into Vs region), extract A-frags into registers ----
  {
    const short* qp = qb + (size_t)(n0 + krow0) * CCH + kch * 8;
#pragma unroll
    for (int i = 0; i < 8; ++i) {
      bf16x8 t = *(const bf16x8*)(qp + (size_t)i * 8 * CCH);
      *(bf16x8*)(Vs + (krow0 + 8 * i) * 256 + koff) = t;
    }
  }
  __syncthreads();
  bf16x8 a_q[8];
  {
    int row = w * 16 + l16;
#pragma unroll
    for (int kc = 0; kc < 8; ++kc)
      a_q[kc] = *(bf16x8*)(Vs + row * 256 + (((kc * 4 + quad) ^ (row & 7)) * 8));
  }
  // ---- prefetch tile 0 into regs ----
  bf16x8 kreg[8], vreg[8];
  {
    const short* kp = kb + (size_t)krow0 * CCH + kch * 8;
    const short* vp = vb + (size_t)vrow0 * NSP + vch * 8;
#pragma unroll
    for (int i = 0; i < 8; ++i) kreg[i] = *(const bf16x8*)(kp + (size_t)i * 8 * CCH);
#pragma unroll
    for (int i = 0; i < 8; ++i) vreg[i] = *(const bf16x8*)(vp + (size_t)i * 32 * NSP);
  }
  __syncthreads();  // drains a_q reads; all waves done with Q before overwrite
#pragma unroll
  for (int i = 0; i < 8; ++i) *(bf16x8*)(Ks + (krow0 + 8 * i) * 256 + koff) = kreg[i];
#pragma unroll
  for (int i = 0; i < 8; ++i) *(bf16x8*)(Vs + (vrow0 + 32 * i) * 64 + voff) = vreg[i];
  __syncthreads();

  f32x4 accO[16];
#pragma unroll
  for (int cb = 0; cb < 16; ++cb) accO[cb] = (f32x4){0.f, 0.f, 0.f, 0.f};
  float m_run[4] = {-1e30f, -1e30f, -1e30f, -1e30f};
  float l_run[4] = {0.f, 0.f, 0.f, 0.f};

#pragma unroll 1
  for (int t = 0; t < 64; ++t) {
    if (t < 63) {  // issue next tile's loads; they land during this compute
      int m0 = (t + 1) * 64;
      const short* kp = kb + (size_t)(m0 + krow0) * CCH + kch * 8;
      const short* vp = vb + (size_t)vrow0 * NSP + m0 + vch * 8;
#pragma unroll
      for (int i = 0; i < 8; ++i) kreg[i] = *(const bf16x8*)(kp + (size_t)i * 8 * CCH);
#pragma unroll
      for (int i = 0; i < 8; ++i) vreg[i] = *(const bf16x8*)(vp + (size_t)i * 32 * NSP);
    }
    // ---- S = Q K^T : 4 mblocks x 8 kchunks ----
    f32x4 s[4];
#pragma unroll
    for (int mb = 0; mb < 4; ++mb) s[mb] = (f32x4){0.f, 0.f, 0.f, 0.f};
#pragma unroll
    for (int kc = 0; kc < 8; ++kc) {
#pragma unroll
      for (int mb = 0; mb < 4; ++mb) {
        int row = mb * 16 + l16;
        bf16x8 bf = *(bf16x8*)(Ks + row * 256 + (((kc * 4 + quad) ^ (row & 7)) * 8));
        s[mb] = __builtin_amdgcn_mfma_f32_16x16x32_bf16(a_q[kc], bf, s[mb], 0, 0, 0);
      }
    }
    // ---- online softmax (rows quad*4+reg; cols l16+16*mb) ----
    float mx[4], alpha[4], ls[4];
#pragma unroll
    for (int r = 0; r < 4; ++r)
      mx[r] = fmaxf(fmaxf(s[0][r], s[1][r]), fmaxf(s[2][r], s[3][r]));
#pragma unroll
    for (int off = 1; off < 16; off <<= 1)
#pragma unroll
      for (int r = 0; r < 4; ++r) mx[r] = fmaxf(mx[r], __shfl_xor(mx[r], off, 16));
#pragma unroll
    for (int r = 0; r < 4; ++r) {
      float mnew = fmaxf(m_run[r], mx[r]);
      alpha[r] = __expf(m_run[r] - mnew);
      m_run[r] = mnew;
      ls[r] = 0.f;
    }
#pragma unroll
    for (int mb = 0; mb < 4; ++mb)
#pragma unroll
      for (int r = 0; r < 4; ++r) {
        float p = __expf(s[mb][r] - m_run[r]);
        s[mb][r] = p;
        ls[r] += p;
      }
#pragma unroll
    for (int off = 1; off < 16; off <<= 1)
#pragma unroll
      for (int r = 0; r < 4; ++r) ls[r] += __shfl_xor(ls[r], off, 16);
    f32x4 alphav;
#pragma unroll
    for (int r = 0; r < 4; ++r) {
      l_run[r] = l_run[r] * alpha[r] + ls[r];
      alphav[r] = alpha[r];
    }
#pragma unroll
    for (int cb = 0; cb < 16; ++cb) accO[cb] *= alphav;
    // ---- P: C-layout -> bf16 A-layout via per-wave LDS ----
#pragma unroll
    for (int mb = 0; mb < 4; ++mb)
#pragma unroll
      for (int r = 0; r < 4; ++r) {
        int prow = quad * 4 + r;
        int pcol = mb * 16 + l16;
        Ps[(w * 16 + prow) * 64 + (((pcol >> 3) ^ (prow & 7)) * 8) + (pcol & 7)] =
            f2bf(s[mb][r]);
      }
    bf16x8 pa[2];
#pragma unroll
    for (int ks = 0; ks < 2; ++ks)
      pa[ks] = *(bf16x8*)(Ps + (w * 16 + l16) * 64 +
                          (((ks * 4 + quad) ^ (l16 & 7)) * 8));
    // ---- O += P V^T : 16 cblocks x 2 ksteps ----
#pragma unroll
    for (int cb = 0; cb < 16; ++cb) {
#pragma unroll
      for (int ks = 0; ks < 2; ++ks) {
        int vrow = cb * 16 + l16;
        bf16x8 bf = *(bf16x8*)(Vs + vrow * 64 + (((ks * 4 + quad) ^ (vrow & 7)) * 8));
        accO[cb] = __builtin_amdgcn_mfma_f32_16x16x32_bf16(pa[ks], bf, accO[cb], 0, 0, 0);
      }
    }
    __syncthreads();  // all waves done reading Ks/Vs
    if (t < 63) {
#pragma unroll
      for (int i = 0; i < 8; ++i) *(bf16x8*)(Ks + (krow0 + 8 * i) * 256 + koff) = kreg[i];
#pragma unroll
      for (int i = 0; i < 8; ++i) *(bf16x8*)(Vs + (vrow0 + 32 * i) * 64 + voff) = vreg[i];
      __syncthreads();
    }
  }
  // ---- epilogue: normalize, LDS transpose, coalesced [c][n] fp32 store ----
  float linv[4];
#pragma unroll
  for (int r = 0; r < 4; ++r) linv[r] = 1.f / l_run[r];
#pragma unroll
  for (int cb = 0; cb < 16; ++cb)
#pragma unroll
    for (int r = 0; r < 4; ++r)
      Fo[(cb * 16 + l16) * 68 + w * 16 + quad * 4 + r] = accO[cb][r] * linv[r];
  __syncthreads();
  float* ob = o + (size_t)b * CCH * NSP;
#pragma unroll
  for (int i = 0; i < 16; ++i) {
    int idx = tid + 256 * i;
    int c = idx >> 4, ng = (idx & 15) * 4;
    *(float4*)(ob + (size_t)c * NSP + n0 + ng) = *(float4*)&Fo[c * 68 + ng];
  }
}

// ---------------- proj + residual + /sqrt(2) (unchanged) ----------------
__global__ __launch_bounds__(256) void proj_kernel(
    const float* __restrict__ ho, const float* __restrict__ Wp,
    const float* __restrict__ bp, const float* __restrict__ x,
    float* __restrict__ out) {
  __shared__ __align__(16) float Ws[32][64];
  __shared__ __align__(16) float Hs[32][64];
  int n0 = blockIdx.x * 64;
  int d0 = blockIdx.y * 64;
  int b = blockIdx.z;
  const float* hb = ho + (size_t)b * CCH * NSP;
  int tid = threadIdx.x;
  int tx = tid & 15, ty = tid >> 4;
  int col = tid & 63, r0 = tid >> 6;
  float acc[4][4] = {};
  for (int c0 = 0; c0 < CCH; c0 += 32) {
#pragma unroll
    for (int r = 0; r < 32; r += 4) {
      Ws[r + r0][col] = Wp[(size_t)(c0 + r + r0) * CCH + d0 + col];
      Hs[r + r0][col] = hb[(size_t)(c0 + r + r0) * NSP + n0 + col];
    }
    __syncthreads();
    for (int cc = 0; cc < 32; ++cc) {
      float4 w4 = *(const float4*)&Ws[cc][ty * 4];
      float4 h4 = *(const float4*)&Hs[cc][tx * 4];
      const float wr[4] = {w4.x, w4.y, w4.z, w4.w};
      const float hr[4] = {h4.x, h4.y, h4.z, h4.w};
#pragma unroll
      for (int i = 0; i < 4; ++i)
#pragma unroll
        for (int j = 0; j < 4; ++j) acc[i][j] += wr[i] * hr[j];
    }
    __syncthreads();
  }
#pragma unroll
  for (int i = 0; i < 4; ++i) {
    int d = d0 + ty * 4 + i;
    float bi = bp[d];
    size_t off = ((size_t)b * CCH + d) * NSP + n0 + tx * 4;
    float4 xr = *(const float4*)(x + off);
    float4 r;
    r.x = (acc[i][0] + bi + xr.x) * RSQRT2;
    r.y = (acc[i][1] + bi + xr.y) * RSQRT2;
    r.z = (acc[i][2] + bi + xr.z) * RSQRT2;
    r.w = (acc[i][3] + bi + xr.w) * RSQRT2;
    *(float4*)(out + off) = r;
  }
}

extern "C" void kernel_launch(void* const* d_in, const int* in_sizes, int n_in,
                              void* d_out, int out_size, void* d_ws, size_t ws_size,
                              hipStream_t stream) {
  const float* x  = (const float*)d_in[0];
  const float* gw = (const float*)d_in[1];
  const float* gb = (const float*)d_in[2];
  const float* Wq = (const float*)d_in[3];
  const float* bq = (const float*)d_in[4];
  const float* Wk = (const float*)d_in[5];
  const float* bk = (const float*)d_in[6];
  const float* Wv = (const float*)d_in[7];
  const float* bv = (const float*)d_in[8];
  const float* Wp = (const float*)d_in[9];
  const float* bp = (const float*)d_in[10];
  float* out = (float*)d_out;

  const size_t SZ = (size_t)BB * CCH * NSP;
  float* h  = (float*)d_ws;          // fp32 h; later attn output (proj input)
  short* qb = (short*)(h + SZ);      // bf16 [b][n][c], pre-scaled
  short* kb = qb + SZ;               // bf16 [b][n][c]
  short* vb = kb + SZ;               // bf16 [b][c][n]   (total ~42 MB)

  gn_kernel<<<dim3(BB * 32), dim3(256), 0, stream>>>(x, gw, gb, h);
  qkv_kernel<<<dim3(64, 4, 12), dim3(256), 0, stream>>>(
      h, Wq, bq, Wk, bk, Wv, bv, qb, kb, vb);
  attn_kernel<<<dim3(256), dim3(256), 0, stream>>>(qb, kb, vb, h);
  proj_kernel<<<dim3(64, 4, BB), dim3(256), 0, stream>>>(h, Wp, bp, x, out);
}